// Round 9
// baseline (274.631 us; speedup 1.0000x reference)
//
#include <hip/hip_runtime.h>

#define NW 3         // waves per block
#define NTH 192
#define TPW 3        // 16-edge MFMA tiles per wave (t)
#define EPW 48       // edges per wave
#define EPB 144      // edges per block
#define STRIDE 168   // bf16 feature stride: 336 B/row, 84 dw -> 2-way bank alias = free

using f32x4 = __attribute__((ext_vector_type(4))) float;
using bf8   = __attribute__((ext_vector_type(8))) short;

__device__ __forceinline__ ushort f2bf(float f) {
    union { float f; unsigned u; } c{f};
    unsigned u = c.u;
    return (ushort)((u + 0x7fffu + ((u >> 16) & 1u)) >> 16);   // RTNE
}

__device__ __forceinline__ unsigned cvt_pk_bf16(float lo, float hi) {
    unsigned r;
    asm("v_cvt_pk_bf16_f32 %0, %1, %2" : "=v"(r) : "v"(lo), "v"(hi));
    return r;
}

// async global->LDS, 16B per lane; LDS dest = wave-uniform base + lane*16
__device__ __forceinline__ void gload_lds16(const void* g, void* l) {
    __builtin_amdgcn_global_load_lds(
        (const __attribute__((address_space(1))) unsigned int*)g,
        (__attribute__((address_space(3))) unsigned int*)l, 16, 0, 0);
}

// ---------------- weight repack: f32 [K][N] -> bf16 A-fragment lines ----------------
// A-frag (mfma_f32_16x16x32_bf16): lane l holds A[m=l&15][k=(l>>4)*8+j], j=0..7
// line (nt*KS+ks) = 512 ushorts = 1KB; frag[line*512 + l*8 + j]
__global__ void repack_kernel(const float* __restrict__ Wstart,
                              const float* __restrict__ Wh0,
                              const float* __restrict__ Wh1,
                              const float* __restrict__ Wh2,
                              ushort* __restrict__ frag) {
    int i = blockIdx.x * blockDim.x + threadIdx.x;
    if (i < 4608) {                       // start: 9 nt * 1 ks * 64 * 8
        int j = i & 7, l = (i >> 3) & 63, nt = i >> 9;
        int k = ((l >> 4) << 3) + j;
        int n = nt * 16 + (l & 15);
        frag[i] = f2bf(Wstart[k * 144 + n]);
    } else if (i < 73728) {               // hidden: 3 * (9 nt * 5 ks * 64 * 8)
        int r = i - 4608;
        int h = r / 23040; r %= 23040;
        const float* W = (h == 0) ? Wh0 : ((h == 1) ? Wh1 : Wh2);
        int j = r & 7, l = (r >> 3) & 63, rem = r >> 9;
        int ks = rem % 5, nt = rem / 5;
        int k = ks * 32 + ((l >> 4) << 3) + j;
        int n = nt * 16 + (l & 15);
        float v = (k < 144) ? W[k * 144 + n] : 0.0f;
        frag[i] = f2bf(v);
    }
}

// stage nlines 1KB fragment lines into wbuf (lines split across the 3 waves)
__device__ __forceinline__ void stage_lines(const ushort* __restrict__ src,
                                            ushort* __restrict__ wbuf,
                                            int nlines, int wave, int lane) {
    for (int l = wave; l < nlines; l += NW)
        gload_lds16(src + (l << 9) + (lane << 3), wbuf + (l << 9));
}

// ---- compute nt range [NTB,NTE): weights from wbuf slots (nt-NTB)*KS+k ----
// C layout: col (l&15)=edge-in-16, row ((l>>4)*4+r)=out-feature [HW-verified]
template<int KS, int NTB, int NTE, bool FINAL>
__device__ __forceinline__ void half_compute(const ushort* __restrict__ wbuf,
                                             const float* __restrict__ bias,
                                             const float* __restrict__ W_end,
                                             ushort (*aw)[STRIDE],
                                             const bf8 (&xf)[TPW][KS],
                                             float* part, int lane) {
    const int grp = lane >> 4, er = lane & 15;
    #pragma unroll
    for (int nt = NTB; nt < NTE; nt++) {
        bf8 wf[KS];
        #pragma unroll
        for (int k = 0; k < KS; k++)
            wf[k] = *(const bf8*)&wbuf[(((nt - NTB) * KS + k) << 9) + (lane << 3)];
        float4 b4 = *(const float4*)&bias[nt * 16 + grp * 4];
        f32x4 bv; bv[0] = b4.x; bv[1] = b4.y; bv[2] = b4.z; bv[3] = b4.w;
        f32x4 acc[TPW] = {bv, bv, bv};
        #pragma unroll
        for (int k = 0; k < KS; k++)
            #pragma unroll
            for (int t = 0; t < TPW; t++)
                acc[t] = __builtin_amdgcn_mfma_f32_16x16x32_bf16(wf[k], xf[t][k], acc[t], 0, 0, 0);
        if constexpr (FINAL) {
            float4 wv = *(const float4*)&W_end[nt * 16 + grp * 4];
            #pragma unroll
            for (int t = 0; t < TPW; t++)
                part[t] += fmaxf(acc[t][0], 0.f) * wv.x + fmaxf(acc[t][1], 0.f) * wv.y
                         + fmaxf(acc[t][2], 0.f) * wv.z + fmaxf(acc[t][3], 0.f) * wv.w;
        } else {
            #pragma unroll
            for (int t = 0; t < TPW; t++) {
                uint2 o;
                o.x = cvt_pk_bf16(fmaxf(acc[t][0], 0.f), fmaxf(acc[t][1], 0.f));
                o.y = cvt_pk_bf16(fmaxf(acc[t][2], 0.f), fmaxf(acc[t][3], 0.f));
                *(uint2*)&aw[t * 16 + er][nt * 16 + grp * 4] = o;
            }
        }
    }
}

// ---- one hidden layer: halfA in wbuf on entry; stages halfB inside; if !LAST stages next halfA ----
template<bool FINAL>
__device__ __forceinline__ void hidden_layer(const ushort* __restrict__ frag_layer,
                                             const ushort* __restrict__ frag_next,
                                             const float* __restrict__ bias,
                                             const float* __restrict__ W_end,
                                             ushort* __restrict__ wbuf,
                                             ushort (*aw)[STRIDE],
                                             float* part, int wave, int lane) {
    const int grp = lane >> 4, er = lane & 15;
    bf8 xf[TPW][5];
    #pragma unroll
    for (int t = 0; t < TPW; t++)
        #pragma unroll
        for (int k = 0; k < 5; k++)
            xf[t][k] = *(const bf8*)&aw[t * 16 + er][k * 32 + grp * 8];
    half_compute<5, 0, 5, FINAL>(wbuf, bias, W_end, aw, xf, part, lane);
    __syncthreads();                                    // all waves done with halfA weights
    stage_lines(frag_layer + 25 * 512, wbuf, 20, wave, lane);
    __syncthreads();                                    // halfB staged (barrier drains vmcnt)
    half_compute<5, 5, 9, FINAL>(wbuf, bias, W_end, aw, xf, part, lane);
    if constexpr (!FINAL) {
        __syncthreads();
        stage_lines(frag_next, wbuf, 25, wave, lane);
        __syncthreads();
    }
}

__global__ __launch_bounds__(NTH, 1)
void mlp_kernel(const float* __restrict__ score,
                const int* __restrict__ label_idx,
                const float* __restrict__ b_start,
                const float* __restrict__ b_h0,
                const float* __restrict__ b_h1,
                const float* __restrict__ b_h2,
                const float* __restrict__ W_end,
                const float* __restrict__ b_end,
                const ushort* __restrict__ frag,
                float* __restrict__ out, int E) {
    __shared__ ushort act[NW][EPW][STRIDE];   // 48384 B: per-wave private tiles
    __shared__ ushort wbuf[25 * 512];         // 25600 B: shared half-layer weights
    const int tid  = threadIdx.x;
    const int lane = tid & 63;
    const int wave = tid >> 6;
    const int grp = lane >> 4, er = lane & 15;
    ushort (*aw)[STRIDE] = act[wave];
    const long e0w = (long)blockIdx.x * EPB + wave * EPW;   // this wave's first edge

    const ushort* fh0 = frag + 4608;
    const ushort* fh1 = fh0 + 23040;
    const ushort* fh2 = fh1 + 23040;

    // stage start-layer weights (9 lines) while gathering
    stage_lines(frag, wbuf, 9, wave, lane);

    // zero K-pad cols 144..159 (never written by epilogues)
    {
        uint4 z = {0u, 0u, 0u, 0u};
        #pragma unroll
        for (int i = lane; i < 96; i += 64)
            *(uint4*)&aw[i >> 1][144 + ((i & 1) << 3)] = z;
    }

    // gather: 48 edges x 32 idx = 384 int4 loads per wave, guarded for the ragged tail
    const int4* lidx4 = (const int4*)label_idx + e0w * 8;
    #pragma unroll
    for (int q = 0; q < 6; q++) {
        int p = q * 64 + lane;
        int el = p >> 3;
        int4 v = (e0w + el < E) ? lidx4[p] : int4{0, 0, 0, 0};
        float f0 = score[v.x], f1 = score[v.y], f2 = score[v.z], f3 = score[v.w];
        uint2 o;
        o.x = cvt_pk_bf16(f0, f1);
        o.y = cvt_pk_bf16(f2, f3);
        *(uint2*)&aw[el][(p & 7) << 2] = o;
    }
    __syncthreads();   // start weights staged + gather visible (self-reads only, but cheap)

    float part[TPW] = {0.f, 0.f, 0.f};

    // start layer (K=32, 9 lines already in wbuf)
    {
        bf8 xf0[TPW][1];
        #pragma unroll
        for (int t = 0; t < TPW; t++)
            xf0[t][0] = *(const bf8*)&aw[t * 16 + er][grp * 8];
        half_compute<1, 0, 9, false>(wbuf, b_start, nullptr, aw, xf0, part, lane);
        __syncthreads();
        stage_lines(fh0, wbuf, 25, wave, lane);
        __syncthreads();
    }

    hidden_layer<false>(fh0, fh1, b_h0, nullptr, wbuf, aw, part, wave, lane);
    hidden_layer<false>(fh1, fh2, b_h1, nullptr, wbuf, aw, part, wave, lane);
    hidden_layer<true >(fh2, nullptr, b_h2, W_end, wbuf, aw, part, wave, lane);

    // reduce W_end partial dots across the 4 lane-groups; store this wave's 48 outputs
    #pragma unroll
    for (int t = 0; t < TPW; t++) {
        part[t] += __shfl_xor(part[t], 16, 64);
        part[t] += __shfl_xor(part[t], 32, 64);
    }
    if (lane < 16) {
        float be = b_end[0];
        #pragma unroll
        for (int t = 0; t < TPW; t++) {
            long e = e0w + t * 16 + lane;
            if (e < E) out[e] = be + part[t];
        }
    }
}

extern "C" void kernel_launch(void* const* d_in, const int* in_sizes, int n_in,
                              void* d_out, int out_size, void* d_ws, size_t ws_size,
                              hipStream_t stream) {
    const float* score   = (const float*)d_in[0];
    const int*   lidx    = (const int*)  d_in[1];
    const float* W_start = (const float*)d_in[2];
    const float* b_start = (const float*)d_in[3];
    const float* W_h0    = (const float*)d_in[4];
    const float* b_h0    = (const float*)d_in[5];
    const float* W_h1    = (const float*)d_in[6];
    const float* b_h1    = (const float*)d_in[7];
    const float* W_h2    = (const float*)d_in[8];
    const float* b_h2    = (const float*)d_in[9];
    const float* W_end   = (const float*)d_in[10];
    const float* b_end   = (const float*)d_in[11];
    float* out = (float*)d_out;

    ushort* frag = (ushort*)d_ws;   // 73728 bf16 = 147456 B of repacked weights

    const int E = in_sizes[1] / 32;   // label_idx is [E][32]; in_sizes is FLAT count

    repack_kernel<<<288, 256, 0, stream>>>(W_start, W_h0, W_h1, W_h2, frag);

    const int nblk = (E + EPB - 1) / EPB;
    mlp_kernel<<<nblk, NTH, 0, stream>>>(score, lidx, b_start, b_h0, b_h1, b_h2,
                                         W_end, b_end, frag, out, E);
}